// Round 1
// baseline (3141.458 us; speedup 1.0000x reference)
//
#include <hip/hip_runtime.h>
#include <math.h>

#define BB 16
#define NN 1024
#define DD 256

// ---------------------------------------------------------------- helpers
#define ACC16(wv, xv) do { \
  acc[0][0] += wv.x*xv.x; acc[0][1] += wv.x*xv.y; acc[0][2] += wv.x*xv.z; acc[0][3] += wv.x*xv.w; \
  acc[1][0] += wv.y*xv.x; acc[1][1] += wv.y*xv.y; acc[1][2] += wv.y*xv.z; acc[1][3] += wv.y*xv.w; \
  acc[2][0] += wv.z*xv.x; acc[2][1] += wv.z*xv.y; acc[2][2] += wv.z*xv.z; acc[2][3] += wv.z*xv.w; \
  acc[3][0] += wv.w*xv.x; acc[3][1] += wv.w*xv.y; acc[3][2] += wv.w*xv.z; acc[3][3] += wv.w*xv.w; \
} while(0)

__device__ __forceinline__ float waveRedSum(float v) {
  #pragma unroll
  for (int o = 32; o; o >>= 1) v += __shfl_xor(v, o, 64);
  return v;
}
__device__ __forceinline__ float waveRedMax(float v) {
  #pragma unroll
  for (int o = 32; o; o >>= 1) v = fmaxf(v, __shfl_xor(v, o, 64));
  return v;
}

// ---------------------------------------------------------------- pts
__global__ void k_pts(const float* __restrict__ x, float* __restrict__ pts) {
  int i = blockIdx.x * 256 + threadIdx.x;            // b*N + n
  if (i >= BB * NN) return;
  int b = i >> 10, n = i & 1023;
  const float* xb = x + (size_t)b * 3 * NN;
  pts[i * 3 + 0] = xb[n];
  pts[i * 3 + 1] = xb[NN + n];
  pts[i * 3 + 2] = xb[2 * NN + n];
}

// ---------------------------------------------------------------- phases eA, eP
__global__ void k_phase(const float* __restrict__ pts, const float* __restrict__ A,
                        const float* __restrict__ P, float2* __restrict__ eA,
                        float2* __restrict__ eP) {
  int i = blockIdx.x * 256 + threadIdx.x;            // (b*N+n)*256 + d
  int d = i & 255; int bn = i >> 8;
  float p0 = pts[bn * 3], p1 = pts[bn * 3 + 1], p2 = pts[bn * 3 + 2];
  float ta = p0 * A[d] + p1 * A[256 + d] + p2 * A[512 + d];
  float tp = p0 * P[d] + p1 * P[256 + d] + p2 * P[512 + d];
  float s, c;
  sincosf(ta, &s, &c); eA[i] = make_float2(c, s);
  sincosf(tp, &s, &c); eP[i] = make_float2(c, s);
}

// ---------------------------------------------------------------- M = J @ eA (J generated in LDS)
__launch_bounds__(256)
__global__ void k_jgemm(const float* __restrict__ pts, const float2* __restrict__ eA,
                        float2* __restrict__ M) {
  int b = blockIdx.x >> 5;
  int n0 = (blockIdx.x & 31) * 32;
  int c = threadIdx.x;                               // channel 0..255
  __shared__ float pn[32][3];
  __shared__ float pm[64][3];
  __shared__ float J[64][32];                        // [m][r]
  if (c < 96) pn[c / 3][c % 3] = pts[((size_t)b * NN + n0) * 3 + c];
  float2 acc[32];
  #pragma unroll
  for (int r = 0; r < 32; r++) acc[r] = make_float2(0.f, 0.f);
  for (int mt = 0; mt < NN; mt += 64) {
    __syncthreads();
    if (c < 192) pm[c / 3][c % 3] = pts[((size_t)b * NN + mt) * 3 + c];
    __syncthreads();
    #pragma unroll
    for (int k = 0; k < 8; k++) {
      int e = c * 8 + k; int m = e >> 5, r = e & 31;
      float dx = pm[m][0] - pn[r][0];
      float dy = pm[m][1] - pn[r][1];
      float dz = pm[m][2] - pn[r][2];
      J[m][r] = __expf(-18.0f * (dx * dx + dy * dy + dz * dz));
    }
    __syncthreads();
    const float2* ebase = eA + ((size_t)b * NN + mt) * DD + c;
    #pragma unroll 4
    for (int m = 0; m < 64; m++) {
      float2 e = ebase[(size_t)m * DD];
      #pragma unroll
      for (int r = 0; r < 32; r += 4) {
        float4 j4 = *(const float4*)&J[m][r];
        acc[r + 0].x += j4.x * e.x; acc[r + 0].y += j4.x * e.y;
        acc[r + 1].x += j4.y * e.x; acc[r + 1].y += j4.y * e.y;
        acc[r + 2].x += j4.z * e.x; acc[r + 2].y += j4.z * e.y;
        acc[r + 3].x += j4.w * e.x; acc[r + 3].y += j4.w * e.y;
      }
    }
  }
  #pragma unroll
  for (int r = 0; r < 32; r++)
    M[((size_t)b * NN + n0 + r) * DD + c] = acc[r];
}

// ---------------------------------------------------------------- G = norm(M*conj(eA))*16 + eP
__global__ void k_norm(const float2* __restrict__ M, const float2* __restrict__ eA,
                       const float2* __restrict__ eP, float2* __restrict__ G) {
  int bn = blockIdx.x; int c = threadIdx.x;
  size_t idx = (size_t)bn * DD + c;
  float2 m = M[idx], e = eA[idx];
  float gr = m.x * e.x + m.y * e.y;
  float gi = m.y * e.x - m.x * e.y;
  float s = gr * gr + gi * gi;
  s = waveRedSum(s);
  __shared__ float red[4];
  if ((c & 63) == 0) red[c >> 6] = s;
  __syncthreads();
  float tot = red[0] + red[1] + red[2] + red[3];
  float scale = 16.0f / sqrtf(tot);
  float2 p = eP[idx];
  G[idx] = make_float2(gr * scale + p.x, gi * scale + p.y);
}

// ---------------------------------------------------------------- combine w into float2
__global__ void k_wc(const float* __restrict__ wr, const float* __restrict__ wi,
                     float2* __restrict__ wc) {
  int i = blockIdx.x * 256 + threadIdx.x;
  wc[i] = make_float2(wr[i], wi[i]);
}

// ---------------------------------------------------------------- complex linear (+opt crelu)
__launch_bounds__(256)
__global__ void k_clinear(const float2* __restrict__ in, const float2* __restrict__ wc,
                          const float* __restrict__ br, const float* __restrict__ bi,
                          float2* __restrict__ out, int relu) {
  int r0 = blockIdx.x * 32;
  int o0 = blockIdx.y * 128;
  int t = threadIdx.x;
  int ro = t >> 5, co = t & 31;
  __shared__ float2 inS[32][33];    // [cc][row]
  __shared__ float2 wS[32][129];    // [cc][o]
  float2 acc[4][4];
  #pragma unroll
  for (int i = 0; i < 4; i++)
    #pragma unroll
    for (int j = 0; j < 4; j++) acc[i][j] = make_float2(0.f, 0.f);
  for (int c0 = 0; c0 < DD; c0 += 32) {
    __syncthreads();
    {
      int r = t >> 3, cc = (t & 7) * 4;
      const float2* p = in + (size_t)(r0 + r) * DD + c0 + cc;
      float2 v0 = p[0], v1 = p[1], v2 = p[2], v3 = p[3];
      inS[cc + 0][r] = v0; inS[cc + 1][r] = v1; inS[cc + 2][r] = v2; inS[cc + 3][r] = v3;
    }
    #pragma unroll
    for (int g = 0; g < 4; g++) {
      int idx = g * 1024 + t * 4;
      int o = idx >> 5, cc = idx & 31;
      const float2* p = wc + (size_t)(o0 + o) * DD + c0 + cc;
      wS[cc + 0][o] = p[0]; wS[cc + 1][o] = p[1]; wS[cc + 2][o] = p[2]; wS[cc + 3][o] = p[3];
    }
    __syncthreads();
    #pragma unroll
    for (int cc = 0; cc < 32; cc++) {
      float2 a0 = inS[cc][ro * 4 + 0];
      float2 a1 = inS[cc][ro * 4 + 1];
      float2 a2 = inS[cc][ro * 4 + 2];
      float2 a3 = inS[cc][ro * 4 + 3];
      float2 w0 = wS[cc][co], w1 = wS[cc][co + 32], w2 = wS[cc][co + 64], w3 = wS[cc][co + 96];
      #define CF(i, j, A, W) \
        acc[i][j].x += A.x * W.x - A.y * W.y; \
        acc[i][j].y += A.x * W.y + A.y * W.x;
      CF(0,0,a0,w0) CF(0,1,a0,w1) CF(0,2,a0,w2) CF(0,3,a0,w3)
      CF(1,0,a1,w0) CF(1,1,a1,w1) CF(1,2,a1,w2) CF(1,3,a1,w3)
      CF(2,0,a2,w0) CF(2,1,a2,w1) CF(2,2,a2,w2) CF(2,3,a2,w3)
      CF(3,0,a3,w0) CF(3,1,a3,w1) CF(3,2,a3,w2) CF(3,3,a3,w3)
      #undef CF
    }
  }
  #pragma unroll
  for (int j = 0; j < 4; j++) {
    int o = o0 + co + j * 32;
    float2 bb = make_float2(br[o], bi[o]);
    #pragma unroll
    for (int i = 0; i < 4; i++) {
      float2 v = make_float2(acc[i][j].x + bb.x, acc[i][j].y + bb.y);
      if (relu) { v.x = fmaxf(v.x, 0.f); v.y = fmaxf(v.y, 0.f); }
      out[(size_t)(r0 + ro * 4 + i) * DD + o] = v;
    }
  }
}

// ---------------------------------------------------------------- Gr = |G|^2, transpose -> big[1024..1279]
__global__ void k_gr(const float2* __restrict__ Gf, float* __restrict__ big) {
  int bid = blockIdx.x;
  int b = bid >> 8, ct = (bid >> 5) & 7, nt = bid & 31;
  int c0 = ct * 32, n0 = nt * 32;
  int t = threadIdx.x;
  __shared__ float tile[32][33];    // [n][c]
  {
    int n = t >> 3, c4 = (t & 7) * 4;
    const float2* p = Gf + ((size_t)b * NN + n0 + n) * DD + c0 + c4;
    #pragma unroll
    for (int k = 0; k < 4; k++) {
      float2 v = p[k];
      tile[n][c4 + k] = v.x * v.x + v.y * v.y;
    }
  }
  __syncthreads();
  {
    int c = t >> 3, n4 = (t & 7) * 4;
    float* po = big + ((size_t)b * 1280 + 1024 + c0 + c) * NN + n0 + n4;
    float4 v = make_float4(tile[n4][c], tile[n4 + 1][c], tile[n4 + 2][c], tile[n4 + 3][c]);
    *(float4*)po = v;
  }
}

// ---------------------------------------------------------------- generic conv GEMM: out = act(bn(W@X + bias)) [+res]
__launch_bounds__(256)
__global__ void k_conv(const float* __restrict__ X, long x_bs,
                       const float* __restrict__ W, int Cc, int numOt,
                       const float* __restrict__ bias,
                       const float* __restrict__ bng, const float* __restrict__ bnb,
                       int act,
                       const float* __restrict__ res, long res_bs,
                       float* __restrict__ out, long out_bs) {
  int bid = blockIdx.x;
  int nt = bid & 15; int tmp = bid >> 4;
  int ot = tmp % numOt; int b = tmp / numOt;
  int n0 = nt * 64, o0 = ot * 64;
  int t = threadIdx.x;
  int to = t >> 4, tn = t & 15;
  __shared__ float Xs[32][64];      // [cc][n]
  __shared__ float Ws[32][72];      // [cc][o]
  float acc[4][4] = {};
  for (int c0 = 0; c0 < Cc; c0 += 32) {
    __syncthreads();
    {
      int cc = t >> 3, n8 = (t & 7) * 8;
      const float* p = X + (long)b * x_bs + (long)(c0 + cc) * NN + n0 + n8;
      float4 v0 = *(const float4*)p;
      float4 v1 = *(const float4*)(p + 4);
      *(float4*)&Xs[cc][n8] = v0;
      *(float4*)&Xs[cc][n8 + 4] = v1;
    }
    {
      int o = t >> 2, c8 = (t & 3) * 8;
      const float* p = W + (long)(o0 + o) * Cc + c0 + c8;
      float4 w0 = *(const float4*)p;
      float4 w1 = *(const float4*)(p + 4);
      Ws[c8 + 0][o] = w0.x; Ws[c8 + 1][o] = w0.y; Ws[c8 + 2][o] = w0.z; Ws[c8 + 3][o] = w0.w;
      Ws[c8 + 4][o] = w1.x; Ws[c8 + 5][o] = w1.y; Ws[c8 + 6][o] = w1.z; Ws[c8 + 7][o] = w1.w;
    }
    __syncthreads();
    #pragma unroll
    for (int cc = 0; cc < 32; cc++) {
      float4 xv = *(const float4*)&Xs[cc][tn * 4];
      float4 wv = *(const float4*)&Ws[cc][to * 4];
      ACC16(wv, xv);
    }
  }
  const float BNS = 0.99999500003749966f;   // 1/sqrt(1+1e-5)
  #pragma unroll
  for (int i = 0; i < 4; i++) {
    int o = o0 + to * 4 + i;
    float mult = 1.f, add = 0.f;
    if (bias) add = bias[o];
    if (bng) { float s = bng[o] * BNS; add = add * s + bnb[o]; mult = s; }
    float4 v;
    v.x = acc[i][0] * mult + add;
    v.y = acc[i][1] * mult + add;
    v.z = acc[i][2] * mult + add;
    v.w = acc[i][3] * mult + add;
    if (act == 1) {
      v.x = fmaxf(v.x, 0.f); v.y = fmaxf(v.y, 0.f); v.z = fmaxf(v.z, 0.f); v.w = fmaxf(v.w, 0.f);
    } else if (act == 2) {
      v.x = v.x > 0.f ? v.x : 0.2f * v.x; v.y = v.y > 0.f ? v.y : 0.2f * v.y;
      v.z = v.z > 0.f ? v.z : 0.2f * v.z; v.w = v.w > 0.f ? v.w : 0.2f * v.w;
    }
    if (res) {
      const float* pr = res + (long)b * res_bs + (long)o * NN + n0 + tn * 4;
      v.x += pr[0]; v.y += pr[1]; v.z += pr[2]; v.w += pr[3];
    }
    *(float4*)(out + (long)b * out_bs + (long)o * NN + n0 + tn * 4) = v;
  }
}

// ---------------------------------------------------------------- energy = xk^T xk
__launch_bounds__(256)
__global__ void k_energy(const float* __restrict__ xk, float* __restrict__ E) {
  int bid = blockIdx.x;
  int mt = bid & 15, nt = (bid >> 4) & 15, b = bid >> 8;
  int n0 = nt * 64, m0 = mt * 64;
  int t = threadIdx.x; int tn = t >> 4, tm = t & 15;
  __shared__ float An[64][64], Am[64][64];    // [o][n], [o][m]
  {
    int o = t >> 2;
    #pragma unroll
    for (int g = 0; g < 2; g++) {
      int c8 = (t & 3) * 16 + g * 8;
      const float* pn = xk + ((long)b * 64 + o) * NN + n0 + c8;
      const float* pm = xk + ((long)b * 64 + o) * NN + m0 + c8;
      *(float4*)&An[o][c8] = *(const float4*)pn;
      *(float4*)&An[o][c8 + 4] = *(const float4*)(pn + 4);
      *(float4*)&Am[o][c8] = *(const float4*)pm;
      *(float4*)&Am[o][c8 + 4] = *(const float4*)(pm + 4);
    }
  }
  __syncthreads();
  float acc[4][4] = {};
  #pragma unroll 8
  for (int o = 0; o < 64; o++) {
    float4 a = *(const float4*)&An[o][tn * 4];
    float4 bm = *(const float4*)&Am[o][tm * 4];
    ACC16(a, bm);
  }
  #pragma unroll
  for (int i = 0; i < 4; i++) {
    float4 v = make_float4(acc[i][0], acc[i][1], acc[i][2], acc[i][3]);
    *(float4*)(E + ((long)b * NN + n0 + tn * 4 + i) * NN + m0 + tm * 4) = v;
  }
}

// ---------------------------------------------------------------- row softmax (in place)
__global__ void k_softmax(float* __restrict__ att) {
  int row = blockIdx.x;
  float* p = att + (size_t)row * NN;
  int t = threadIdx.x;
  float4 v = *(float4*)(p + t * 4);
  float mx = fmaxf(fmaxf(v.x, v.y), fmaxf(v.z, v.w));
  mx = waveRedMax(mx);
  __shared__ float redm[4];
  __shared__ float reds[4];
  if ((t & 63) == 0) redm[t >> 6] = mx;
  __syncthreads();
  mx = fmaxf(fmaxf(redm[0], redm[1]), fmaxf(redm[2], redm[3]));
  v.x = __expf(v.x - mx); v.y = __expf(v.y - mx);
  v.z = __expf(v.z - mx); v.w = __expf(v.w - mx);
  float s = v.x + v.y + v.z + v.w;
  s = waveRedSum(s);
  if ((t & 63) == 0) reds[t >> 6] = s;
  __syncthreads();
  s = reds[0] + reds[1] + reds[2] + reds[3];
  float inv = 1.0f / s;
  v.x *= inv; v.y *= inv; v.z *= inv; v.w *= inv;
  *(float4*)(p + t * 4) = v;
}

// ---------------------------------------------------------------- column sums of att
__global__ void k_colsum(const float* __restrict__ att, float* __restrict__ colsum) {
  int bid = blockIdx.x;                       // b*16 + mt
  int b = bid >> 4, m0 = (bid & 15) * 64;
  int t = threadIdx.x; int tm = t & 63, tn = t >> 6;
  const float* p = att + (size_t)b * NN * NN + m0 + tm;
  float s = 0.f;
  for (int n = tn; n < NN; n += 4) s += p[(size_t)n * NN];
  __shared__ float red[4][64];
  red[tn][tm] = s;
  __syncthreads();
  if (t < 64) colsum[b * NN + m0 + t] = red[0][t] + red[1][t] + red[2][t] + red[3][t];
}

// ---------------------------------------------------------------- diff = Xin - (xv@att)/colsum
__launch_bounds__(256)
__global__ void k_xr(const float* __restrict__ xv, const float* __restrict__ att,
                     const float* __restrict__ colsum,
                     const float* __restrict__ Xin, long xin_bs,
                     float* __restrict__ diff) {
  int bid = blockIdx.x;
  int mt = bid & 15; int ct = (bid >> 4) & 3; int b = bid >> 6;
  int c0 = ct * 64, m0 = mt * 64;
  int t = threadIdx.x; int tc = t >> 4, tm = t & 15;
  __shared__ float As[32][72];   // [n][c]
  __shared__ float Bs[32][64];   // [n][m]
  float acc[4][4] = {};
  for (int nB = 0; nB < NN; nB += 32) {
    __syncthreads();
    {
      int c = t >> 2, n8 = (t & 3) * 8;
      const float* p = xv + ((long)b * 256 + c0 + c) * NN + nB + n8;
      float4 v0 = *(const float4*)p;
      float4 v1 = *(const float4*)(p + 4);
      As[n8 + 0][c] = v0.x; As[n8 + 1][c] = v0.y; As[n8 + 2][c] = v0.z; As[n8 + 3][c] = v0.w;
      As[n8 + 4][c] = v1.x; As[n8 + 5][c] = v1.y; As[n8 + 6][c] = v1.z; As[n8 + 7][c] = v1.w;
    }
    {
      int nn = t >> 3, m8 = (t & 7) * 8;
      const float* p = att + ((long)b * NN + nB + nn) * NN + m0 + m8;
      *(float4*)&Bs[nn][m8] = *(const float4*)p;
      *(float4*)&Bs[nn][m8 + 4] = *(const float4*)(p + 4);
    }
    __syncthreads();
    #pragma unroll
    for (int nn = 0; nn < 32; nn++) {
      float4 av = *(const float4*)&As[nn][tc * 4];
      float4 bv = *(const float4*)&Bs[nn][tm * 4];
      ACC16(av, bv);
    }
  }
  float inv[4];
  #pragma unroll
  for (int j = 0; j < 4; j++)
    inv[j] = 1.0f / (1e-9f + colsum[b * NN + m0 + tm * 4 + j]);
  #pragma unroll
  for (int i = 0; i < 4; i++) {
    int c = c0 + tc * 4 + i;
    const float* px = Xin + (long)b * xin_bs + (long)c * NN + m0 + tm * 4;
    float4 v;
    v.x = px[0] - acc[i][0] * inv[0];
    v.y = px[1] - acc[i][1] * inv[1];
    v.z = px[2] - acc[i][2] * inv[2];
    v.w = px[3] - acc[i][3] * inv[3];
    *(float4*)(diff + ((long)b * 256 + c) * NN + m0 + tm * 4) = v;
  }
}

// ---------------------------------------------------------------- max pool over N
__global__ void k_maxpool(const float* __restrict__ fin, float* __restrict__ pool) {
  int bo = blockIdx.x;                       // b*1024 + o
  const float* p = fin + (size_t)bo * NN;
  int t = threadIdx.x;
  float m = fmaxf(fmaxf(p[t], p[t + 256]), fmaxf(p[t + 512], p[t + 768]));
  m = waveRedMax(m);
  __shared__ float red[4];
  if ((t & 63) == 0) red[t >> 6] = m;
  __syncthreads();
  if (t == 0) pool[bo] = fmaxf(fmaxf(red[0], red[1]), fmaxf(red[2], red[3]));
}

// ---------------------------------------------------------------- small FC layers
__global__ void k_fc(const float* __restrict__ in, int Cc,
                     const float* __restrict__ W,
                     const float* __restrict__ bias,
                     const float* __restrict__ bng, const float* __restrict__ bnb,
                     int act, float* __restrict__ out, int O) {
  int i = blockIdx.x * 256 + threadIdx.x;
  if (i >= BB * O) return;
  int b = i / O, o = i % O;
  const float* xp = in + (size_t)b * Cc;
  const float* wp = W + (size_t)o * Cc;
  float s = 0.f;
  for (int c = 0; c < Cc; c += 4) {
    float4 xv = *(const float4*)(xp + c);
    float4 wv = *(const float4*)(wp + c);
    s += xv.x * wv.x + xv.y * wv.y + xv.z * wv.z + xv.w * wv.w;
  }
  if (bias) s += bias[o];
  const float BNS = 0.99999500003749966f;
  if (bng) s = s * (bng[o] * BNS) + bnb[o];
  if (act == 2) s = s > 0.f ? s : 0.2f * s;
  else if (act == 1) s = fmaxf(s, 0.f);
  out[i] = s;
}

// ---------------------------------------------------------------- host
extern "C" void kernel_launch(void* const* d_in, const int* in_sizes, int n_in,
                              void* d_out, int out_size, void* d_ws, size_t ws_size,
                              hipStream_t stream) {
  const float* x        = (const float*)d_in[0];
  const float* A        = (const float*)d_in[1];
  const float* P        = (const float*)d_in[2];
  const float* cl1_wr   = (const float*)d_in[3];
  const float* cl1_wi   = (const float*)d_in[4];
  const float* cl1_br   = (const float*)d_in[5];
  const float* cl1_bi   = (const float*)d_in[6];
  const float* cl2_wr   = (const float*)d_in[7];
  const float* cl2_wi   = (const float*)d_in[8];
  const float* cl2_br   = (const float*)d_in[9];
  const float* cl2_bi   = (const float*)d_in[10];
  const float* pt_c1_w  = (const float*)d_in[11];
  const float* pt_c2_w  = (const float*)d_in[12];
  const float* pt_bn1_g = (const float*)d_in[13];
  const float* pt_bn1_b = (const float*)d_in[14];
  const float* pt_bn2_g = (const float*)d_in[15];
  const float* pt_bn2_b = (const float*)d_in[16];
  const float* sa_qk_w  = (const float*)d_in[17];
  const float* sa_v_w   = (const float*)d_in[18];
  const float* sa_v_b   = (const float*)d_in[19];
  const float* sa_t_w   = (const float*)d_in[20];
  const float* sa_t_b   = (const float*)d_in[21];
  const float* sa_bn_g  = (const float*)d_in[22];
  const float* sa_bn_b  = (const float*)d_in[23];
  const float* fuse_w   = (const float*)d_in[24];
  const float* fuse_g   = (const float*)d_in[25];
  const float* fuse_b   = (const float*)d_in[26];
  const float* lin1_w   = (const float*)d_in[27];
  const float* bn6_g    = (const float*)d_in[28];
  const float* bn6_b    = (const float*)d_in[29];
  const float* lin2_w   = (const float*)d_in[30];
  const float* lin2_b   = (const float*)d_in[31];
  const float* bn7_g    = (const float*)d_in[32];
  const float* bn7_b    = (const float*)d_in[33];
  const float* lin3_w   = (const float*)d_in[34];
  const float* lin3_b   = (const float*)d_in[35];

  float* ws = (float*)d_ws;
  // workspace layout (float offsets)
  const size_t oPts  = 0;
  const size_t oR    = 65536;                 // 33554432-float aliased region
  const size_t oeA   = oR;                    // phase 1
  const size_t oeP   = oR + 8388608;
  const size_t obufA = oR + 16777216;
  const size_t obufB = oR + 25165824;
  const size_t oAtt  = oR;                    // phase 2 (SA)
  const size_t oXk   = oR + 16777216;
  const size_t oXv   = oXk + 1048576;
  const size_t oDiff = oXv + 4194304;
  const size_t oFuse = oR;                    // phase 3 (fuse out)
  const size_t oBig  = oR + 33554432;         // [B,1280,N]
  const size_t oH1   = oBig + 20971520;
  const size_t oH2   = oH1 + 4194304;
  const size_t oCs   = oH2 + 4194304;
  const size_t oPool = oCs + 16384;
  const size_t oFc1  = oPool + 16384;
  const size_t oFc2  = oFc1 + 8192;
  const size_t oWc1  = oFc2 + 4096;
  const size_t oWc2  = oWc1 + 131072;

  float*  pts  = ws + oPts;
  float2* eA   = (float2*)(ws + oeA);
  float2* eP   = (float2*)(ws + oeP);
  float2* bufA = (float2*)(ws + obufA);
  float2* bufB = (float2*)(ws + obufB);
  float*  att  = ws + oAtt;
  float*  xk   = ws + oXk;
  float*  xv   = ws + oXv;
  float*  diff = ws + oDiff;
  float*  fuseO= ws + oFuse;
  float*  big  = ws + oBig;
  float*  h1   = ws + oH1;
  float*  h2   = ws + oH2;
  float*  cs   = ws + oCs;
  float*  pool = ws + oPool;
  float*  fc1  = ws + oFc1;
  float*  fc2  = ws + oFc2;
  float2* wc1  = (float2*)(ws + oWc1);
  float2* wc2  = (float2*)(ws + oWc2);

  const long bsH  = 256L * NN;    // packed [B,256,N]
  const long bsBig= 1280L * NN;
  const long bsXk = 64L * NN;
  const long bs1024 = 1024L * NN;

  // ---- VecKM ----
  k_pts<<<64, 256, 0, stream>>>(x, pts);
  k_phase<<<16384, 256, 0, stream>>>(pts, A, P, eA, eP);
  k_jgemm<<<512, 256, 0, stream>>>(pts, eA, bufA);
  k_norm<<<BB * NN, 256, 0, stream>>>(bufA, eA, eP, bufA);

  // ---- complex linears ----
  k_wc<<<256, 256, 0, stream>>>(cl1_wr, cl1_wi, wc1);
  k_wc<<<256, 256, 0, stream>>>(cl2_wr, cl2_wi, wc2);
  k_clinear<<<dim3(512, 2), 256, 0, stream>>>(bufA, wc1, cl1_br, cl1_bi, bufB, 1);
  k_clinear<<<dim3(512, 2), 256, 0, stream>>>(bufB, wc2, cl2_br, cl2_bi, bufA, 0);
  k_gr<<<4096, 256, 0, stream>>>(bufA, big);

  // ---- point transformer front convs ----
  float* Gc = big + 1024L * NN;  // slice ptr (batch stride bsBig)
  k_conv<<<BB * 4 * 16, 256, 0, stream>>>(Gc, bsBig, pt_c1_w, 256, 4,
      nullptr, pt_bn1_g, pt_bn1_b, 1, nullptr, 0, h1, bsH);
  k_conv<<<BB * 4 * 16, 256, 0, stream>>>(h1, bsH, pt_c2_w, 256, 4,
      nullptr, pt_bn2_g, pt_bn2_b, 1, nullptr, 0, h2, bsH);

  // ---- 4 SA layers ----
  for (int i = 0; i < 4; i++) {
    const float* Xin = (i == 0) ? h2 : (big + (long)(i - 1) * 256 * NN);
    long xin_bs = (i == 0) ? bsH : bsBig;
    const float* qkw = sa_qk_w + (size_t)i * 64 * 256;
    const float* vw  = sa_v_w + (size_t)i * 256 * 256;
    const float* vb  = sa_v_b + (size_t)i * 256;
    const float* tw  = sa_t_w + (size_t)i * 256 * 256;
    const float* tb  = sa_t_b + (size_t)i * 256;
    const float* bg  = sa_bn_g + (size_t)i * 256;
    const float* bb  = sa_bn_b + (size_t)i * 256;
    float* outSlice = big + (long)i * 256 * NN;

    k_conv<<<BB * 1 * 16, 256, 0, stream>>>(Xin, xin_bs, qkw, 256, 1,
        nullptr, nullptr, nullptr, 0, nullptr, 0, xk, bsXk);
    k_conv<<<BB * 4 * 16, 256, 0, stream>>>(Xin, xin_bs, vw, 256, 4,
        vb, nullptr, nullptr, 0, nullptr, 0, xv, bsH);
    k_energy<<<BB * 16 * 16, 256, 0, stream>>>(xk, att);
    k_softmax<<<BB * NN, 256, 0, stream>>>(att);
    k_colsum<<<BB * 16, 256, 0, stream>>>(att, cs);
    k_xr<<<BB * 4 * 16, 256, 0, stream>>>(xv, att, cs, Xin, xin_bs, diff);
    k_conv<<<BB * 4 * 16, 256, 0, stream>>>(diff, bsH, tw, 256, 4,
        tb, bg, bb, 1, Xin, xin_bs, outSlice, bsBig);
  }

  // ---- fuse conv + pool ----
  k_conv<<<BB * 16 * 16, 256, 0, stream>>>(big, bsBig, fuse_w, 1280, 16,
      nullptr, fuse_g, fuse_b, 2, nullptr, 0, fuseO, bs1024);
  k_maxpool<<<BB * 1024, 256, 0, stream>>>(fuseO, pool);

  // ---- MLP head ----
  k_fc<<<32, 256, 0, stream>>>(pool, 1024, lin1_w, nullptr, bn6_g, bn6_b, 2, fc1, 512);
  k_fc<<<16, 256, 0, stream>>>(fc1, 512, lin2_w, lin2_b, bn7_g, bn7_b, 2, fc2, 256);
  k_fc<<<3, 256, 0, stream>>>(fc2, 256, lin3_w, lin3_b, nullptr, nullptr, 0, (float*)d_out, 40);
}

// Round 2
// 1748.400 us; speedup vs baseline: 1.7968x; 1.7968x over previous
//
#include <hip/hip_runtime.h>
#include <math.h>

#define BB 16
#define NN 1024
#define DD 256

typedef unsigned short u16;
typedef unsigned int uint32;
typedef __attribute__((ext_vector_type(8))) short s8v;   // 8 bf16 (4 VGPRs)
typedef __attribute__((ext_vector_type(4))) float f4v;   // 4 fp32 acc

__device__ __forceinline__ u16 f2b(float f) {            // RNE fp32->bf16
  uint32 u = __float_as_uint(f);
  return (u16)((u + 0x7fffu + ((u >> 16) & 1u)) >> 16);
}
__device__ __forceinline__ float b2f(u16 u) {
  return __uint_as_float(((uint32)u) << 16);
}

__device__ __forceinline__ float waveRedSum(float v) {
  #pragma unroll
  for (int o = 32; o; o >>= 1) v += __shfl_xor(v, o, 64);
  return v;
}
__device__ __forceinline__ float waveRedMax(float v) {
  #pragma unroll
  for (int o = 32; o; o >>= 1) v = fmaxf(v, __shfl_xor(v, o, 64));
  return v;
}

// ---------------------------------------------------------------- pts [B,N,3]
__global__ void k_pts(const float* __restrict__ x, float* __restrict__ pts) {
  int i = blockIdx.x * 256 + threadIdx.x;
  if (i >= BB * NN) return;
  int b = i >> 10, n = i & 1023;
  const float* xb = x + (size_t)b * 3 * NN;
  pts[i * 3 + 0] = xb[n];
  pts[i * 3 + 1] = xb[NN + n];
  pts[i * 3 + 2] = xb[2 * NN + n];
}

// ---------------------------------------------------------------- eA only (eP folded into k_norm)
__global__ void k_phase(const float* __restrict__ pts, const float* __restrict__ A,
                        float2* __restrict__ eA) {
  int i = blockIdx.x * 256 + threadIdx.x;            // (b*N+n)*256 + d
  int d = i & 255; int bn = i >> 8;
  float p0 = pts[bn * 3], p1 = pts[bn * 3 + 1], p2 = pts[bn * 3 + 2];
  float ta = p0 * A[d] + p1 * A[256 + d] + p2 * A[512 + d];
  float s, c;
  sincosf(ta, &s, &c); eA[i] = make_float2(c, s);
}

// ---------------------------------------------------------------- M = J @ eA (J generated in LDS), fp32
__launch_bounds__(256)
__global__ void k_jgemm(const float* __restrict__ pts, const float2* __restrict__ eA,
                        float2* __restrict__ M) {
  int b = blockIdx.x >> 5;
  int n0 = (blockIdx.x & 31) * 32;
  int c = threadIdx.x;
  __shared__ float pn[32][3];
  __shared__ float pm[64][3];
  __shared__ float J[64][32];
  if (c < 96) pn[c / 3][c % 3] = pts[((size_t)b * NN + n0) * 3 + c];
  float2 acc[32];
  #pragma unroll
  for (int r = 0; r < 32; r++) acc[r] = make_float2(0.f, 0.f);
  for (int mt = 0; mt < NN; mt += 64) {
    __syncthreads();
    if (c < 192) pm[c / 3][c % 3] = pts[((size_t)b * NN + mt) * 3 + c];
    __syncthreads();
    #pragma unroll
    for (int k = 0; k < 8; k++) {
      int e = c * 8 + k; int m = e >> 5, r = e & 31;
      float dx = pm[m][0] - pn[r][0];
      float dy = pm[m][1] - pn[r][1];
      float dz = pm[m][2] - pn[r][2];
      J[m][r] = __expf(-18.0f * (dx * dx + dy * dy + dz * dz));
    }
    __syncthreads();
    const float2* ebase = eA + ((size_t)b * NN + mt) * DD + c;
    #pragma unroll 4
    for (int m = 0; m < 64; m++) {
      float2 e = ebase[(size_t)m * DD];
      #pragma unroll
      for (int r = 0; r < 32; r += 4) {
        float4 j4 = *(const float4*)&J[m][r];
        acc[r + 0].x += j4.x * e.x; acc[r + 0].y += j4.x * e.y;
        acc[r + 1].x += j4.y * e.x; acc[r + 1].y += j4.y * e.y;
        acc[r + 2].x += j4.z * e.x; acc[r + 2].y += j4.z * e.y;
        acc[r + 3].x += j4.w * e.x; acc[r + 3].y += j4.w * e.y;
      }
    }
  }
  #pragma unroll
  for (int r = 0; r < 32; r++)
    M[((size_t)b * NN + n0 + r) * DD + c] = acc[r];
}

// ------------------------------------------ G = norm(M*conj(eA))*16 + exp(i pts@P) -> interleaved bf16 [bn][512]
__global__ void k_norm(const float2* __restrict__ M, const float2* __restrict__ eA,
                       const float* __restrict__ pts, const float* __restrict__ P,
                       u16* __restrict__ Gb) {
  int bn = blockIdx.x; int c = threadIdx.x;
  size_t idx = (size_t)bn * DD + c;
  float2 m = M[idx], e = eA[idx];
  float gr = m.x * e.x + m.y * e.y;
  float gi = m.y * e.x - m.x * e.y;
  float s = gr * gr + gi * gi;
  s = waveRedSum(s);
  __shared__ float red[4];
  if ((c & 63) == 0) red[c >> 6] = s;
  __syncthreads();
  float tot = red[0] + red[1] + red[2] + red[3];
  float scale = 16.0f / sqrtf(tot);
  float p0 = pts[bn * 3], p1 = pts[bn * 3 + 1], p2 = pts[bn * 3 + 2];
  float tp = p0 * P[c] + p1 * P[256 + c] + p2 * P[512 + c];
  float sp, cp; sincosf(tp, &sp, &cp);
  uint32 pk = (uint32)f2b(gr * scale + cp) | ((uint32)f2b(gi * scale + sp) << 16);
  *(uint32*)(Gb + idx * 2) = pk;
}

// ---------------------------------------------------------------- weight casts / complex-weight prep
__global__ void k_cast(const float* __restrict__ s, u16* __restrict__ d, int n) {
  int i = blockIdx.x * 256 + threadIdx.x;
  if (i < n) d[i] = f2b(s[i]);
}
// B' for complex linear: rows 0..255 = [Wr,-Wi] interleaved; 256..511 = [Wi,Wr]
__global__ void k_wprep(const float* __restrict__ wr, const float* __restrict__ wi,
                        u16* __restrict__ dst) {
  int i = blockIdx.x * 256 + threadIdx.x;   // 512*512
  int op = i >> 9, c2 = i & 511, c = c2 >> 1, pl = c2 & 1;
  float v;
  if (op < 256) v = pl ? -wi[op * 256 + c] : wr[op * 256 + c];
  else          v = pl ?  wr[(op - 256) * 256 + c] : wi[(op - 256) * 256 + c];
  dst[i] = f2b(v);
}
__global__ void k_cbias(const float* __restrict__ br, const float* __restrict__ bi,
                        float* __restrict__ cb) {
  int t = threadIdx.x;
  cb[t] = (t < 256) ? br[t] : bi[t - 256];
}

// ---------------------------------------------------------------- Gr=|G|^2 -> bigT[:,1024+c] bf16
__global__ void k_g2(const u16* __restrict__ G2b, u16* __restrict__ bigT) {
  int i = blockIdx.x * 256 + threadIdx.x;   // 16384*256
  int row = i >> 8, c = i & 255;
  float re = b2f(G2b[(size_t)row * 512 + 2 * c]);
  float im = b2f(G2b[(size_t)row * 512 + 2 * c + 1]);
  bigT[(size_t)row * 1280 + 1024 + c] = f2b(re * re + im * im);
}

// ---------------------------------------------------------------- att fp32 [n][m] -> attT bf16 [m][n]
__global__ void k_tc(const float* __restrict__ X, u16* __restrict__ Xt) {
  int bid = blockIdx.x;
  int mt = bid & 15, nt = (bid >> 4) & 15, b = bid >> 8;
  int n0 = nt * 64, m0 = mt * 64;
  __shared__ float tile[64][65];
  int t = threadIdx.x;
  int r = t >> 4, c4 = (t & 15) * 4;
  const float* src = X + ((size_t)b << 20);
  #pragma unroll
  for (int it = 0; it < 4; it++) {
    float4 v = *(const float4*)(src + (size_t)(n0 + r + it * 16) * 1024 + m0 + c4);
    tile[r + it * 16][c4 + 0] = v.x; tile[r + it * 16][c4 + 1] = v.y;
    tile[r + it * 16][c4 + 2] = v.z; tile[r + it * 16][c4 + 3] = v.w;
  }
  __syncthreads();
  u16* dst = Xt + ((size_t)b << 20);
  #pragma unroll
  for (int it = 0; it < 4; it++) {
    int m = r + it * 16;
    uint32 lo = (uint32)f2b(tile[c4 + 0][m]) | ((uint32)f2b(tile[c4 + 1][m]) << 16);
    uint32 hi = (uint32)f2b(tile[c4 + 2][m]) | ((uint32)f2b(tile[c4 + 3][m]) << 16);
    *(uint2*)(dst + (size_t)(m0 + m) * 1024 + n0 + c4) = make_uint2(lo, hi);
  }
}

// ---------------------------------------------------------------- generic bf16 MFMA GEMM
// D[M][N] = A[M][K] * Bt[N][K]^T  (both bf16, k-contiguous), fp32 accum.
// Epilogue: v = acc; if(colsum) v/=cs[no]; v = v*bnscale + (bias*bnscale+bnb);
//           if(cbias) v+=cb[no]; act; if(res) v = res_sub ? res-v : res+v.
// Outputs: outF fp32 [mo][no] (ld ldF), outB bf16 [mo][no or interleaved], outT bf16 [no][mo] (ld ldT).
template<int BM>
__launch_bounds__(256)
__global__ void k_mm(const u16* __restrict__ Ab, long a_bs, int lda,
                     const u16* __restrict__ Btb, long b_bs, int ldb,
                     int K, int tiles_m, int tiles_n,
                     const float* __restrict__ bias,
                     const float* __restrict__ bng, const float* __restrict__ bnb,
                     const float* __restrict__ cbias,
                     const float* __restrict__ colsum, long cs_bs,
                     int act,
                     const float* __restrict__ res, long res_bs, int res_sub,
                     float* __restrict__ outF, long outF_bs, int ldF,
                     u16* __restrict__ outB, long outB_bs, int ldBo, int ileave,
                     u16* __restrict__ outT, long outT_bs, int ldT) {
  constexpr int BN = 128;
  constexpr int WM = (BM == 128) ? 64 : 32;
  constexpr int MI = WM / 16;
  __shared__ u16 smem[BN * BM];            // >= As(BM*32)+Bs(BN*32); also T[BN][BM]
  u16* As = smem;
  u16* Bs = smem + BM * 32;
  int t = threadIdx.x;
  int l = t & 63, w = t >> 6;
  int p = l & 15, q = l >> 4;
  int bid = blockIdx.x;
  int tn = bid % tiles_n;
  int tm = (bid / tiles_n) % tiles_m;
  int b  = bid / (tiles_n * tiles_m);
  int m0 = tm * BM, n0 = tn * BN;
  int wm = w >> 1, wn = w & 1;
  const u16* Ap = Ab + (size_t)b * a_bs;
  const u16* Bp = Btb + (size_t)b * b_bs;

  f4v acc[MI][4];
  #pragma unroll
  for (int i = 0; i < MI; i++)
    #pragma unroll
    for (int j = 0; j < 4; j++) acc[i][j] = (f4v){0.f, 0.f, 0.f, 0.f};

  int arow = t >> 2, kg = (t & 3) * 8;
  for (int k0 = 0; k0 < K; k0 += 32) {
    __syncthreads();
    #pragma unroll
    for (int it = 0; it < BM / 64; it++) {
      int r = it * 64 + arow;
      float4 v = *(const float4*)(Ap + (size_t)(m0 + r) * lda + k0 + kg);
      *(float4*)&As[r * 32 + kg] = v;
    }
    #pragma unroll
    for (int it = 0; it < 2; it++) {
      int r = it * 64 + arow;
      float4 v = *(const float4*)(Bp + (size_t)(n0 + r) * ldb + k0 + kg);
      *(float4*)&Bs[r * 32 + kg] = v;
    }
    __syncthreads();
    s8v af[MI], bf[4];
    #pragma unroll
    for (int i = 0; i < MI; i++)
      af[i] = *(const s8v*)&As[(wm * WM + i * 16 + p) * 32 + q * 8];
    #pragma unroll
    for (int j = 0; j < 4; j++)
      bf[j] = *(const s8v*)&Bs[(wn * 64 + j * 16 + p) * 32 + q * 8];
    #pragma unroll
    for (int i = 0; i < MI; i++)
      #pragma unroll
      for (int j = 0; j < 4; j++)
        acc[i][j] = __builtin_amdgcn_mfma_f32_16x16x32_bf16(af[i], bf[j], acc[i][j], 0, 0, 0);
  }

  __syncthreads();   // LDS reuse as transpose buffer

  float csv[4], cbv[4];
  #pragma unroll
  for (int j = 0; j < 4; j++) {
    int no = n0 + wn * 64 + j * 16 + p;
    csv[j] = colsum ? 1.0f / (1e-9f + colsum[(size_t)b * cs_bs + no]) : 1.0f;
    cbv[j] = cbias ? cbias[no] : 0.0f;
  }
  const float BNS = 0.99999500003749966f;  // 1/sqrt(1+1e-5)
  #pragma unroll
  for (int i = 0; i < MI; i++) {
    #pragma unroll
    for (int r = 0; r < 4; r++) {
      int mo = m0 + wm * WM + i * 16 + q * 4 + r;
      float mult = 1.f, add = 0.f;
      if (bias) add = bias[mo];
      if (bng) { float s = bng[mo] * BNS; add = add * s + bnb[mo]; mult = s; }
      #pragma unroll
      for (int j = 0; j < 4; j++) {
        int no = n0 + wn * 64 + j * 16 + p;
        float v = acc[i][j][r];
        if (colsum) v *= csv[j];
        v = v * mult + add;
        if (cbias) v += cbv[j];
        if (act == 1) v = fmaxf(v, 0.f);
        else if (act == 2) v = v > 0.f ? v : 0.2f * v;
        if (res) {
          float rv = res[(size_t)b * res_bs + (size_t)mo * NN + no];
          v = res_sub ? rv - v : rv + v;
        }
        if (outF) outF[(size_t)b * outF_bs + (size_t)mo * ldF + no] = v;
        if (outB) {
          int noo = ileave ? (((no & 255) << 1) | (no >> 8)) : no;
          outB[(size_t)b * outB_bs + (size_t)mo * ldBo + noo] = f2b(v);
        }
        if (outT) smem[(wn * 64 + j * 16 + p) * BM + (mo - m0)] = f2b(v);
      }
    }
  }
  if (outT) {
    __syncthreads();
    constexpr int CPR = BM / 8;            // threads per row (8 bf16 each)
    constexpr int RPP = 256 / CPR;
    int row0 = t / CPR, cg = (t % CPR) * 8;
    for (int rr = row0; rr < BN; rr += RPP) {
      float4 v = *(const float4*)&smem[rr * BM + cg];
      *(float4*)(outT + (size_t)b * outT_bs + (size_t)(n0 + rr) * ldT + m0 + cg) = v;
    }
  }
}

// ---------------------------------------------------------------- row softmax fp32 (in place)
__global__ void k_softmax(float* __restrict__ att) {
  int row = blockIdx.x;
  float* pp = att + (size_t)row * NN;
  int t = threadIdx.x;
  float4 v = *(float4*)(pp + t * 4);
  float mx = fmaxf(fmaxf(v.x, v.y), fmaxf(v.z, v.w));
  mx = waveRedMax(mx);
  __shared__ float redm[4];
  __shared__ float reds[4];
  if ((t & 63) == 0) redm[t >> 6] = mx;
  __syncthreads();
  mx = fmaxf(fmaxf(redm[0], redm[1]), fmaxf(redm[2], redm[3]));
  v.x = __expf(v.x - mx); v.y = __expf(v.y - mx);
  v.z = __expf(v.z - mx); v.w = __expf(v.w - mx);
  float s = v.x + v.y + v.z + v.w;
  s = waveRedSum(s);
  if ((t & 63) == 0) reds[t >> 6] = s;
  __syncthreads();
  s = reds[0] + reds[1] + reds[2] + reds[3];
  float inv = 1.0f / s;
  v.x *= inv; v.y *= inv; v.z *= inv; v.w *= inv;
  *(float4*)(pp + t * 4) = v;
}

// ---------------------------------------------------------------- column sums of att (fp32)
__global__ void k_colsum(const float* __restrict__ att, float* __restrict__ colsum) {
  int bid = blockIdx.x;
  int b = bid >> 4, m0 = (bid & 15) * 64;
  int t = threadIdx.x; int tm = t & 63, tn = t >> 6;
  const float* pp = att + (size_t)b * NN * NN + m0 + tm;
  float s = 0.f;
  for (int n = tn; n < NN; n += 4) s += pp[(size_t)n * NN];
  __shared__ float red[4][64];
  red[tn][tm] = s;
  __syncthreads();
  if (t < 64) colsum[b * NN + m0 + t] = red[0][t] + red[1][t] + red[2][t] + red[3][t];
}

// ---------------------------------------------------------------- max pool over N
__global__ void k_maxpool(const float* __restrict__ fin, float* __restrict__ pool) {
  int bo = blockIdx.x;
  const float* pp = fin + (size_t)bo * NN;
  int t = threadIdx.x;
  float m = fmaxf(fmaxf(pp[t], pp[t + 256]), fmaxf(pp[t + 512], pp[t + 768]));
  m = waveRedMax(m);
  __shared__ float red[4];
  if ((t & 63) == 0) red[t >> 6] = m;
  __syncthreads();
  if (t == 0) pool[bo] = fmaxf(fmaxf(red[0], red[1]), fmaxf(red[2], red[3]));
}

// ---------------------------------------------------------------- small FC layers fp32
__global__ void k_fc(const float* __restrict__ in, int Cc,
                     const float* __restrict__ W,
                     const float* __restrict__ bias,
                     const float* __restrict__ bng, const float* __restrict__ bnb,
                     int act, float* __restrict__ out, int O) {
  int i = blockIdx.x * 256 + threadIdx.x;
  if (i >= BB * O) return;
  int b = i / O, o = i % O;
  const float* xp = in + (size_t)b * Cc;
  const float* wp = W + (size_t)o * Cc;
  float s = 0.f;
  for (int c = 0; c < Cc; c += 4) {
    float4 xv = *(const float4*)(xp + c);
    float4 wv = *(const float4*)(wp + c);
    s += xv.x * wv.x + xv.y * wv.y + xv.z * wv.z + xv.w * wv.w;
  }
  if (bias) s += bias[o];
  const float BNS = 0.99999500003749966f;
  if (bng) s = s * (bng[o] * BNS) + bnb[o];
  if (act == 2) s = s > 0.f ? s : 0.2f * s;
  else if (act == 1) s = fmaxf(s, 0.f);
  out[i] = s;
}

// ---------------------------------------------------------------- host
extern "C" void kernel_launch(void* const* d_in, const int* in_sizes, int n_in,
                              void* d_out, int out_size, void* d_ws, size_t ws_size,
                              hipStream_t stream) {
  const float* x        = (const float*)d_in[0];
  const float* A        = (const float*)d_in[1];
  const float* P        = (const float*)d_in[2];
  const float* cl1_wr   = (const float*)d_in[3];
  const float* cl1_wi   = (const float*)d_in[4];
  const float* cl1_br   = (const float*)d_in[5];
  const float* cl1_bi   = (const float*)d_in[6];
  const float* cl2_wr   = (const float*)d_in[7];
  const float* cl2_wi   = (const float*)d_in[8];
  const float* cl2_br   = (const float*)d_in[9];
  const float* cl2_bi   = (const float*)d_in[10];
  const float* pt_c1_w  = (const float*)d_in[11];
  const float* pt_c2_w  = (const float*)d_in[12];
  const float* pt_bn1_g = (const float*)d_in[13];
  const float* pt_bn1_b = (const float*)d_in[14];
  const float* pt_bn2_g = (const float*)d_in[15];
  const float* pt_bn2_b = (const float*)d_in[16];
  const float* sa_qk_w  = (const float*)d_in[17];
  const float* sa_v_w   = (const float*)d_in[18];
  const float* sa_v_b   = (const float*)d_in[19];
  const float* sa_t_w   = (const float*)d_in[20];
  const float* sa_t_b   = (const float*)d_in[21];
  const float* sa_bn_g  = (const float*)d_in[22];
  const float* sa_bn_b  = (const float*)d_in[23];
  const float* fuse_w   = (const float*)d_in[24];
  const float* fuse_g   = (const float*)d_in[25];
  const float* fuse_b   = (const float*)d_in[26];
  const float* lin1_w   = (const float*)d_in[27];
  const float* bn6_g    = (const float*)d_in[28];
  const float* bn6_b    = (const float*)d_in[29];
  const float* lin2_w   = (const float*)d_in[30];
  const float* lin2_b   = (const float*)d_in[31];
  const float* bn7_g    = (const float*)d_in[32];
  const float* bn7_b    = (const float*)d_in[33];
  const float* lin3_w   = (const float*)d_in[34];
  const float* lin3_b   = (const float*)d_in[35];

  float* ws = (float*)d_ws;
  // ---- workspace layout (float offsets), total ~226 MB ----
  const size_t oPts  = 0;                         // 49152
  const size_t oS    = 65536;                     // scratch region, 16777216 f
  const size_t oBigT = oS + 16777216;             // 10485760 f (bf16 [16][1024][1280])
  const size_t oXf0  = oBigT + 10485760;          // 4194304
  const size_t oXf1  = oXf0 + 4194304;            // 4194304
  const size_t oH1T  = oXf1 + 4194304;            // 2097152 (also diffT alias)
  const size_t oH2T  = oH1T + 2097152;            // 2097152
  const size_t oXkT  = oH2T + 2097152;            // 524288
  const size_t oXv   = oXkT + 524288;             // 2097152
  const size_t oAttT = oXv + 2097152;             // 8388608 (bf16 [16][1024][1024])
  const size_t oGb   = oAttT + 8388608;           // 4194304 (bf16 [16384][512])
  const size_t oW1c  = oGb + 4194304;             // 131072
  const size_t oW2c  = oW1c + 131072;             // 131072
  const size_t oCb1  = oW2c + 131072;             // 512
  const size_t oCb2  = oCb1 + 512;                // 512
  const size_t oCs   = oCb2 + 512;                // 16384
  const size_t oPool = oCs + 16384;               // 16384
  const size_t oFc1  = oPool + 16384;             // 8192
  const size_t oFc2  = oFc1 + 8192;               // 4096
  const size_t oWp   = oFc2 + 4096;               // 1015808 (bf16 weight pool)

  float*  pts  = ws + oPts;
  // scratch region S aliases: phase1 eA|Mj ; then G1b|G2b ; then att ; then fuseO
  float2* eA   = (float2*)(ws + oS);              // 4194304 float2
  float2* Mj   = (float2*)(ws + oS + 8388608);
  u16*    G1b  = (u16*)(ws + oS);                 // after eA dead
  u16*    G2b  = (u16*)(ws + oS + 8388608);       // after Mj dead
  float*  att  = ws + oS;                         // after G dead (16777216 f)
  float*  fuseO= ws + oS;                         // after att dead
  u16*    bigT = (u16*)(ws + oBigT);
  float*  Xf0  = ws + oXf0;
  float*  Xf1  = ws + oXf1;
  u16*    h1T  = (u16*)(ws + oH1T);
  u16*    diffT= (u16*)(ws + oH1T);               // alias (h1T dead after pt2)
  u16*    h2T  = (u16*)(ws + oH2T);
  u16*    xkT  = (u16*)(ws + oXkT);
  u16*    xv   = (u16*)(ws + oXv);
  u16*    attT = (u16*)(ws + oAttT);
  u16*    Gb   = (u16*)(ws + oGb);
  u16*    W1c  = (u16*)(ws + oW1c);
  u16*    W2c  = (u16*)(ws + oW2c);
  float*  cb1  = ws + oCb1;
  float*  cb2  = ws + oCb2;
  float*  cs   = ws + oCs;
  float*  pool = ws + oPool;
  float*  fc1  = ws + oFc1;
  float*  fc2  = ws + oFc2;
  u16*    wp   = (u16*)(ws + oWp);
  u16* wp_pt1  = wp;                // 65536
  u16* wp_pt2  = wp + 65536;        // 65536
  u16* wp_qk   = wp + 131072;       // 4*16384
  u16* wp_v    = wp + 196608;       // 4*65536
  u16* wp_t    = wp + 458752;       // 4*65536
  u16* wp_fuse = wp + 720896;       // 1310720

  // ---- weight prep ----
  k_cast<<<256, 256, 0, stream>>>(pt_c1_w, wp_pt1, 65536);
  k_cast<<<256, 256, 0, stream>>>(pt_c2_w, wp_pt2, 65536);
  k_cast<<<256, 256, 0, stream>>>(sa_qk_w, wp_qk, 65536);
  k_cast<<<1024, 256, 0, stream>>>(sa_v_w, wp_v, 262144);
  k_cast<<<1024, 256, 0, stream>>>(sa_t_w, wp_t, 262144);
  k_cast<<<5120, 256, 0, stream>>>(fuse_w, wp_fuse, 1310720);
  k_wprep<<<1024, 256, 0, stream>>>(cl1_wr, cl1_wi, W1c);
  k_wprep<<<1024, 256, 0, stream>>>(cl2_wr, cl2_wi, W2c);
  k_cbias<<<1, 512, 0, stream>>>(cl1_br, cl1_bi, cb1);
  k_cbias<<<1, 512, 0, stream>>>(cl2_br, cl2_bi, cb2);

  // ---- VecKM (fp32) ----
  k_pts<<<64, 256, 0, stream>>>(x, pts);
  k_phase<<<16384, 256, 0, stream>>>(pts, A, eA);
  k_jgemm<<<512, 256, 0, stream>>>(pts, eA, Mj);
  k_norm<<<BB * NN, 256, 0, stream>>>(Mj, eA, pts, P, Gb);

  // ---- complex linears as single real MFMA GEMMs (K=512) ----
  // clinear1: Gb[16384][512] * W1c[512][512]^T -> G1b interleaved, crelu
  k_mm<128><<<512, 256, 0, stream>>>(Gb, 0, 512, W1c, 0, 512, 512, 128, 4,
      nullptr, nullptr, nullptr, cb1, nullptr, 0, 1, nullptr, 0, 0,
      nullptr, 0, 0, G1b, 0, 512, 1, nullptr, 0, 0);
  // clinear2: no act
  k_mm<128><<<512, 256, 0, stream>>>(G1b, 0, 512, W2c, 0, 512, 512, 128, 4,
      nullptr, nullptr, nullptr, cb2, nullptr, 0, 0, nullptr, 0, 0,
      nullptr, 0, 0, G2b, 0, 512, 1, nullptr, 0, 0);
  k_g2<<<16384, 256, 0, stream>>>(G2b, bigT);

  const long bsBigT = 1310720;   // ushort units
  const long bsH256 = 262144;    // [1024][256] ushort
  const long bsXkT  = 65536;
  const long bsXvU  = 262144;    // xv bf16 [256][1024]
  const long bsAttT = 1048576;
  const long bsF    = 262144;    // fp32 [256][1024]
  const long bsAtt  = 1048576;   // fp32 [1024][1024]

  // ---- pt convs ----
  // pt1: W[256][256] * GcT(bigT+1024, ld1280) -> h1T bf16 [n][256]
  k_mm<128><<<256, 256, 0, stream>>>(wp_pt1, 0, 256, bigT + 1024, bsBigT, 1280, 256, 2, 8,
      nullptr, pt_bn1_g, pt_bn1_b, nullptr, nullptr, 0, 1, nullptr, 0, 0,
      nullptr, 0, 0, nullptr, 0, 0, 0, h1T, bsH256, 256);
  // pt2: -> Xf0 fp32 [c][n] + h2T bf16 [n][256]
  k_mm<128><<<256, 256, 0, stream>>>(wp_pt2, 0, 256, h1T, bsH256, 256, 256, 2, 8,
      nullptr, pt_bn2_g, pt_bn2_b, nullptr, nullptr, 0, 1, nullptr, 0, 0,
      Xf0, bsF, 1024, nullptr, 0, 0, 0, h2T, bsH256, 256);

  // ---- 4 SA layers ----
  for (int i = 0; i < 4; i++) {
    const u16* XinT   = (i == 0) ? h2T : (bigT + (i - 1) * 256);
    long       xinT_bs= (i == 0) ? bsH256 : bsBigT;
    int        xinT_ld= (i == 0) ? 256 : 1280;
    float*     XinF   = (i & 1) ? Xf1 : Xf0;
    float*     XoutF  = (i & 1) ? Xf0 : Xf1;
    const u16* qkw = wp_qk + (size_t)i * 16384;
    const u16* vw  = wp_v + (size_t)i * 65536;
    const u16* tw  = wp_t + (size_t)i * 65536;

    // qk conv: [64][256] -> xkT bf16 [n][64]
    k_mm<64><<<128, 256, 0, stream>>>(qkw, 0, 256, XinT, xinT_bs, xinT_ld, 256, 1, 8,
        nullptr, nullptr, nullptr, nullptr, nullptr, 0, 0, nullptr, 0, 0,
        nullptr, 0, 0, nullptr, 0, 0, 0, xkT, bsXkT, 64);
    // v conv: -> xv bf16 [c][n] (+bias)
    k_mm<128><<<256, 256, 0, stream>>>(vw, 0, 256, XinT, xinT_bs, xinT_ld, 256, 2, 8,
        sa_v_b + i * 256, nullptr, nullptr, nullptr, nullptr, 0, 0, nullptr, 0, 0,
        nullptr, 0, 0, xv, bsXvU, 1024, 0, nullptr, 0, 0);
    // energy = xkT * xkT^T -> att fp32 [n][m]
    k_mm<128><<<1024, 256, 0, stream>>>(xkT, bsXkT, 64, xkT, bsXkT, 64, 64, 8, 8,
        nullptr, nullptr, nullptr, nullptr, nullptr, 0, 0, nullptr, 0, 0,
        att, bsAtt, 1024, nullptr, 0, 0, 0, nullptr, 0, 0);
    k_softmax<<<BB * NN, 256, 0, stream>>>(att);
    k_colsum<<<BB * 16, 256, 0, stream>>>(att, cs);
    k_tc<<<4096, 256, 0, stream>>>(att, attT);
    // xr: xv[256][1024] * attT[m][1024]^T, scale by 1/colsum, diff = Xin - ., -> diffT bf16 [m][256]
    k_mm<128><<<256, 256, 0, stream>>>(xv, bsXvU, 1024, attT, bsAttT, 1024, 1024, 2, 8,
        nullptr, nullptr, nullptr, nullptr, cs, 1024, 0, XinF, bsF, 1,
        nullptr, 0, 0, nullptr, 0, 0, 0, diffT, bsH256, 256);
    // t conv: relu(bn(tw@diff + tb)) + Xin -> XoutF fp32 + bigT slice bf16
    k_mm<128><<<256, 256, 0, stream>>>(tw, 0, 256, diffT, bsH256, 256, 256, 2, 8,
        sa_t_b + i * 256, sa_bn_g + i * 256, sa_bn_b + i * 256, nullptr, nullptr, 0, 1,
        XinF, bsF, 0,
        XoutF, bsF, 1024, nullptr, 0, 0, 0, bigT + i * 256, bsBigT, 1280);
  }

  // ---- fuse conv + pool ----
  k_mm<128><<<1024, 256, 0, stream>>>(wp_fuse, 0, 1280, bigT, bsBigT, 1280, 1280, 8, 8,
      nullptr, fuse_g, fuse_b, nullptr, nullptr, 0, 2, nullptr, 0, 0,
      fuseO, 1048576, 1024, nullptr, 0, 0, 0, nullptr, 0, 0);
  k_maxpool<<<BB * 1024, 256, 0, stream>>>(fuseO, pool);

  // ---- MLP head ----
  k_fc<<<32, 256, 0, stream>>>(pool, 1024, lin1_w, nullptr, bn6_g, bn6_b, 2, fc1, 512);
  k_fc<<<16, 256, 0, stream>>>(fc1, 512, lin2_w, lin2_b, bn7_g, bn7_b, 2, fc2, 256);
  k_fc<<<3, 256, 0, stream>>>(fc2, 256, lin3_w, lin3_b, nullptr, nullptr, 0, (float*)d_out, 40);
}

// Round 3
// 1096.241 us; speedup vs baseline: 2.8657x; 1.5949x over previous
//
#include <hip/hip_runtime.h>
#include <math.h>

#define BB 16
#define NN 1024
#define DD 256

typedef unsigned short u16;
typedef unsigned int uint32;
typedef __attribute__((ext_vector_type(8))) short s8v;   // 8 bf16 (4 VGPRs)
typedef __attribute__((ext_vector_type(4))) float f4v;   // 4 fp32 acc

__device__ __forceinline__ u16 f2b(float f) {            // RNE fp32->bf16
  uint32 u = __float_as_uint(f);
  return (u16)((u + 0x7fffu + ((u >> 16) & 1u)) >> 16);
}
__device__ __forceinline__ float b2f(u16 u) {
  return __uint_as_float(((uint32)u) << 16);
}

__device__ __forceinline__ float waveRedSum(float v) {
  #pragma unroll
  for (int o = 32; o; o >>= 1) v += __shfl_xor(v, o, 64);
  return v;
}
__device__ __forceinline__ float waveRedMax(float v) {
  #pragma unroll
  for (int o = 32; o; o >>= 1) v = fmaxf(v, __shfl_xor(v, o, 64));
  return v;
}

// ---------------------------------------------------------------- pts [B,N,3]
__global__ void k_pts(const float* __restrict__ x, float* __restrict__ pts) {
  int i = blockIdx.x * 256 + threadIdx.x;
  if (i >= BB * NN) return;
  int b = i >> 10, n = i & 1023;
  const float* xb = x + (size_t)b * 3 * NN;
  pts[i * 3 + 0] = xb[n];
  pts[i * 3 + 1] = xb[NN + n];
  pts[i * 3 + 2] = xb[2 * NN + n];
}

// ---------------------------------------------------------------- eA fp32 [bn][256] float2
__global__ void k_phase(const float* __restrict__ pts, const float* __restrict__ A,
                        float2* __restrict__ eA) {
  int i = blockIdx.x * 256 + threadIdx.x;            // (b*N+n)*256 + d
  int d = i & 255; int bn = i >> 8;
  float p0 = pts[bn * 3], p1 = pts[bn * 3 + 1], p2 = pts[bn * 3 + 2];
  float ta = p0 * A[d] + p1 * A[256 + d] + p2 * A[512 + d];
  float s, c;
  sincosf(ta, &s, &c); eA[i] = make_float2(c, s);
}

// ---------------------------------------------------------------- eA -> eAT bf16 [b][512][1024] (row 2d=cos, 2d+1=sin)
__global__ void k_eat(const float2* __restrict__ eA, u16* __restrict__ eAT) {
  int bid = blockIdx.x;
  int dt = bid & 7, nt = (bid >> 3) & 15, b = bid >> 7;
  int d0 = dt * 32, n0 = nt * 64;
  __shared__ u16 cosT[32][72], sinT[32][72];
  int t = threadIdx.x;
  {
    int n = t >> 2, dg = (t & 3) * 8;
    const float2* p = eA + ((size_t)(b * 1024 + n0 + n)) * 256 + d0 + dg;
    #pragma unroll
    for (int j = 0; j < 8; j++) {
      float2 v = p[j];
      cosT[dg + j][n] = f2b(v.x);
      sinT[dg + j][n] = f2b(v.y);
    }
  }
  __syncthreads();
  {
    int rr = t >> 2, ng = (t & 3) * 16;
    int d = rr >> 1, cmp = rr & 1;
    const u16* src = (cmp ? &sinT[d][ng] : &cosT[d][ng]);
    uint4 v0 = *(const uint4*)src;
    uint4 v1 = *(const uint4*)(src + 8);
    u16* dst = eAT + ((size_t)(b * 512 + 2 * d0 + rr)) * 1024 + n0 + ng;
    *(uint4*)dst = v0;
    *(uint4*)(dst + 8) = v1;
  }
}

// ---------------------------------------------------------------- J bf16 [b][n][1024]
__global__ void k_jbuild(const float* __restrict__ pts, u16* __restrict__ J) {
  int bid = blockIdx.x;                 // b*1024 + n
  int b = bid >> 10, n = bid & 1023;
  int t = threadIdx.x;
  const float* pb = pts + (size_t)b * 3072;
  float pnx = pb[n * 3], pny = pb[n * 3 + 1], pnz = pb[n * 3 + 2];
  int m = t * 4;
  const float* pm = pb + (size_t)m * 3;
  float4 a = *(const float4*)pm;
  float4 bq = *(const float4*)(pm + 4);
  float4 c = *(const float4*)(pm + 8);
  float dx, dy, dz, d2;
  dx = a.x - pnx;  dy = a.y - pny;  dz = a.z - pnz;  d2 = dx*dx + dy*dy + dz*dz;
  float j0 = __expf(-18.0f * d2);
  dx = a.w - pnx;  dy = bq.x - pny; dz = bq.y - pnz; d2 = dx*dx + dy*dy + dz*dz;
  float j1 = __expf(-18.0f * d2);
  dx = bq.z - pnx; dy = bq.w - pny; dz = c.x - pnz;  d2 = dx*dx + dy*dy + dz*dz;
  float j2 = __expf(-18.0f * d2);
  dx = c.y - pnx;  dy = c.z - pny;  dz = c.w - pnz;  d2 = dx*dx + dy*dy + dz*dz;
  float j3 = __expf(-18.0f * d2);
  uint32 lo = (uint32)f2b(j0) | ((uint32)f2b(j1) << 16);
  uint32 hi = (uint32)f2b(j2) | ((uint32)f2b(j3) << 16);
  *(uint2*)(J + (size_t)bid * 1024 + m) = make_uint2(lo, hi);
}

// ------------------------------------------ G = norm(M*conj(eA))*16 + exp(i pts@P) -> interleaved bf16 [bn][512]
__global__ void k_norm(const float2* __restrict__ M, const float2* __restrict__ eA,
                       const float* __restrict__ pts, const float* __restrict__ P,
                       u16* __restrict__ Gb) {
  int bn = blockIdx.x; int c = threadIdx.x;
  size_t idx = (size_t)bn * DD + c;
  float2 m = M[idx], e = eA[idx];
  float gr = m.x * e.x + m.y * e.y;
  float gi = m.y * e.x - m.x * e.y;
  float s = gr * gr + gi * gi;
  s = waveRedSum(s);
  __shared__ float red[4];
  if ((c & 63) == 0) red[c >> 6] = s;
  __syncthreads();
  float tot = red[0] + red[1] + red[2] + red[3];
  float scale = 16.0f / sqrtf(tot);
  float p0 = pts[bn * 3], p1 = pts[bn * 3 + 1], p2 = pts[bn * 3 + 2];
  float tp = p0 * P[c] + p1 * P[256 + c] + p2 * P[512 + c];
  float sp, cp; sincosf(tp, &sp, &cp);
  uint32 pk = (uint32)f2b(gr * scale + cp) | ((uint32)f2b(gi * scale + sp) << 16);
  *(uint32*)(Gb + idx * 2) = pk;
}

// ---------------------------------------------------------------- weight casts / complex-weight prep
__global__ void k_cast(const float* __restrict__ s, u16* __restrict__ d, int n) {
  int i = blockIdx.x * 256 + threadIdx.x;
  if (i < n) d[i] = f2b(s[i]);
}
// B' for complex linear: rows 0..255 = [Wr,-Wi] interleaved; 256..511 = [Wi,Wr]
__global__ void k_wprep(const float* __restrict__ wr, const float* __restrict__ wi,
                        u16* __restrict__ dst) {
  int i = blockIdx.x * 256 + threadIdx.x;   // 512*512
  int op = i >> 9, c2 = i & 511, c = c2 >> 1, pl = c2 & 1;
  float v;
  if (op < 256) v = pl ? -wi[op * 256 + c] : wr[op * 256 + c];
  else          v = pl ?  wr[(op - 256) * 256 + c] : wi[(op - 256) * 256 + c];
  dst[i] = f2b(v);
}
__global__ void k_cbias(const float* __restrict__ br, const float* __restrict__ bi,
                        float* __restrict__ cb) {
  int t = threadIdx.x;
  cb[t] = (t < 256) ? br[t] : bi[t - 256];
}

// ---------------------------------------------------------------- Gr=|G|^2 -> bigT[:,1024+c] bf16
__global__ void k_g2(const u16* __restrict__ G2b, u16* __restrict__ bigT) {
  int i = blockIdx.x * 256 + threadIdx.x;   // 16384*256
  int row = i >> 8, c = i & 255;
  float re = b2f(G2b[(size_t)row * 512 + 2 * c]);
  float im = b2f(G2b[(size_t)row * 512 + 2 * c + 1]);
  bigT[(size_t)row * 1280 + 1024 + c] = f2b(re * re + im * im);
}

// ---------------------------------------------------------------- generic bf16 MFMA GEMM
// D[M][N] = A[M][K] * Bt[N][K]^T  (both bf16, k-contiguous), fp32 accum.
template<int BM>
__launch_bounds__(256)
__global__ void k_mm(const u16* __restrict__ Ab, long a_bs, int lda,
                     const u16* __restrict__ Btb, long b_bs, int ldb,
                     int K, int tiles_m, int tiles_n,
                     const float* __restrict__ bias,
                     const float* __restrict__ bng, const float* __restrict__ bnb,
                     const float* __restrict__ cbias,
                     int act,
                     const float* __restrict__ res, long res_bs, int res_sub,
                     float* __restrict__ outF, long outF_bs, int ldF,
                     u16* __restrict__ outB, long outB_bs, int ldBo, int ileave,
                     u16* __restrict__ outT, long outT_bs, int ldT) {
  constexpr int BN = 128;
  constexpr int WM = (BM == 128) ? 64 : 32;
  constexpr int MI = WM / 16;
  __shared__ u16 smem[BN * BM];            // >= As(BM*32)+Bs(BN*32); also T[BN][BM]
  u16* As = smem;
  u16* Bs = smem + BM * 32;
  int t = threadIdx.x;
  int l = t & 63, w = t >> 6;
  int p = l & 15, q = l >> 4;
  int bid = blockIdx.x;
  int tn = bid % tiles_n;
  int tm = (bid / tiles_n) % tiles_m;
  int b  = bid / (tiles_n * tiles_m);
  int m0 = tm * BM, n0 = tn * BN;
  int wm = w >> 1, wn = w & 1;
  const u16* Ap = Ab + (size_t)b * a_bs;
  const u16* Bp = Btb + (size_t)b * b_bs;

  f4v acc[MI][4];
  #pragma unroll
  for (int i = 0; i < MI; i++)
    #pragma unroll
    for (int j = 0; j < 4; j++) acc[i][j] = (f4v){0.f, 0.f, 0.f, 0.f};

  int arow = t >> 2, kg = (t & 3) * 8;
  for (int k0 = 0; k0 < K; k0 += 32) {
    __syncthreads();
    #pragma unroll
    for (int it = 0; it < BM / 64; it++) {
      int r = it * 64 + arow;
      float4 v = *(const float4*)(Ap + (size_t)(m0 + r) * lda + k0 + kg);
      *(float4*)&As[r * 32 + kg] = v;
    }
    #pragma unroll
    for (int it = 0; it < 2; it++) {
      int r = it * 64 + arow;
      float4 v = *(const float4*)(Bp + (size_t)(n0 + r) * ldb + k0 + kg);
      *(float4*)&Bs[r * 32 + kg] = v;
    }
    __syncthreads();
    s8v af[MI], bf[4];
    #pragma unroll
    for (int i = 0; i < MI; i++)
      af[i] = *(const s8v*)&As[(wm * WM + i * 16 + p) * 32 + q * 8];
    #pragma unroll
    for (int j = 0; j < 4; j++)
      bf[j] = *(const s8v*)&Bs[(wn * 64 + j * 16 + p) * 32 + q * 8];
    #pragma unroll
    for (int i = 0; i < MI; i++)
      #pragma unroll
      for (int j = 0; j < 4; j++)
        acc[i][j] = __builtin_amdgcn_mfma_f32_16x16x32_bf16(af[i], bf[j], acc[i][j], 0, 0, 0);
  }

  __syncthreads();   // LDS reuse as transpose buffer

  float cbv[4];
  #pragma unroll
  for (int j = 0; j < 4; j++) {
    int no = n0 + wn * 64 + j * 16 + p;
    cbv[j] = cbias ? cbias[no] : 0.0f;
  }
  const float BNS = 0.99999500003749966f;  // 1/sqrt(1+1e-5)
  #pragma unroll
  for (int i = 0; i < MI; i++) {
    #pragma unroll
    for (int r = 0; r < 4; r++) {
      int mo = m0 + wm * WM + i * 16 + q * 4 + r;
      float mult = 1.f, add = 0.f;
      if (bias) add = bias[mo];
      if (bng) { float s = bng[mo] * BNS; add = add * s + bnb[mo]; mult = s; }
      #pragma unroll
      for (int j = 0; j < 4; j++) {
        int no = n0 + wn * 64 + j * 16 + p;
        float v = acc[i][j][r];
        v = v * mult + add;
        if (cbias) v += cbv[j];
        if (act == 1) v = fmaxf(v, 0.f);
        else if (act == 2) v = v > 0.f ? v : 0.2f * v;
        if (res) {
          float rv = res[(size_t)b * res_bs + (size_t)mo * NN + no];
          v = res_sub ? rv - v : rv + v;
        }
        if (outF) outF[(size_t)b * outF_bs + (size_t)mo * ldF + no] = v;
        if (outB) {
          int noo = ileave ? (((no & 255) << 1) | (no >> 8)) : no;
          outB[(size_t)b * outB_bs + (size_t)mo * ldBo + noo] = f2b(v);
        }
        if (outT) smem[(wn * 64 + j * 16 + p) * BM + (mo - m0)] = f2b(v);
      }
    }
  }
  if (outT) {
    __syncthreads();
    constexpr int CPR = BM / 8;            // threads per row (8 bf16 each)
    constexpr int RPP = 256 / CPR;
    int row0 = t / CPR, cg = (t % CPR) * 8;
    for (int rr = row0; rr < BN; rr += RPP) {
      float4 v = *(const float4*)&smem[rr * BM + cg];
      *(float4*)(outT + (size_t)b * outT_bs + (size_t)(n0 + rr) * ldT + m0 + cg) = v;
    }
  }
}

// ---------------------------------------------------------------- row max + 1/sum(exp) of E
__global__ void k_rowstats(const float* __restrict__ E, float* __restrict__ rmax_,
                           float* __restrict__ rinv_) {
  int row = blockIdx.x;                      // b*1024 + n
  const float* pp = E + (size_t)row * NN;
  int t = threadIdx.x;
  float4 v = *(const float4*)(pp + t * 4);
  float mx = fmaxf(fmaxf(v.x, v.y), fmaxf(v.z, v.w));
  mx = waveRedMax(mx);
  __shared__ float redm[4];
  __shared__ float reds[4];
  if ((t & 63) == 0) redm[t >> 6] = mx;
  __syncthreads();
  mx = fmaxf(fmaxf(redm[0], redm[1]), fmaxf(redm[2], redm[3]));
  float s = __expf(v.x - mx) + __expf(v.y - mx) + __expf(v.z - mx) + __expf(v.w - mx);
  s = waveRedSum(s);
  if ((t & 63) == 0) reds[t >> 6] = s;
  __syncthreads();
  if (t == 0) {
    float tot = reds[0] + reds[1] + reds[2] + reds[3];
    rmax_[row] = mx;
    rinv_[row] = 1.0f / tot;
  }
}

// ---------------------------------------------------------------- fused softmax+colsum+xr+diff (uses E symmetry)
// D[c][m] = sum_n xv[c][n] * p[n][m],  p[n][m] = exp(E[m][n]-rmax[n])*rinv[n]  (E symmetric)
// diffT[m][c] = Xin[c][m] - D[c][m] / (1e-9 + colsum[m])
__launch_bounds__(256)
__global__ void k_xratt(const u16* __restrict__ xv_, const float* __restrict__ E,
                        const float* __restrict__ rmax_, const float* __restrict__ rinv_,
                        const float* __restrict__ XinF, long xinF_bs,
                        u16* __restrict__ diffT) {
  __shared__ u16 smem[16384];          // As(0..4095) Bs(4096..8191); reuse as 128x128 transpose
  __shared__ float colred[128][4];
  u16* As = smem;
  u16* Bs = smem + 4096;
  int t = threadIdx.x;
  int l = t & 63, w = t >> 6;
  int p = l & 15, q = l >> 4;
  int bid = blockIdx.x;
  int mt = bid & 7, ct = (bid >> 3) & 1, b = bid >> 4;
  int c0 = ct * 128, m0 = mt * 128;
  int wm = w >> 1, wn = w & 1;
  const u16* Ap = xv_ + (size_t)b * 262144;
  const float* Ep = E + ((size_t)b << 20);
  const float* rmx = rmax_ + (b << 10);
  const float* riv = rinv_ + (b << 10);
  f4v acc[4][4];
  #pragma unroll
  for (int i = 0; i < 4; i++)
    #pragma unroll
    for (int j = 0; j < 4; j++) acc[i][j] = (f4v){0.f, 0.f, 0.f, 0.f};
  float colpart0 = 0.f, colpart1 = 0.f;
  int arow = t >> 2, kg = (t & 3) * 8;
  for (int k0 = 0; k0 < 1024; k0 += 32) {
    __syncthreads();
    #pragma unroll
    for (int it = 0; it < 2; it++) {
      int r = it * 64 + arow;
      *(float4*)&As[r * 32 + kg] = *(const float4*)(Ap + (size_t)(c0 + r) * 1024 + k0 + kg);
    }
    float4 ma0 = *(const float4*)(rmx + k0 + kg);
    float4 ma1 = *(const float4*)(rmx + k0 + kg + 4);
    float4 ia0 = *(const float4*)(riv + k0 + kg);
    float4 ia1 = *(const float4*)(riv + k0 + kg + 4);
    #pragma unroll
    for (int it = 0; it < 2; it++) {
      int r = it * 64 + arow;
      const float* ep = Ep + (size_t)(m0 + r) * 1024 + k0 + kg;
      float4 e0 = *(const float4*)ep;
      float4 e1 = *(const float4*)(ep + 4);
      float p0 = __expf(e0.x - ma0.x) * ia0.x;
      float p1 = __expf(e0.y - ma0.y) * ia0.y;
      float p2 = __expf(e0.z - ma0.z) * ia0.z;
      float p3 = __expf(e0.w - ma0.w) * ia0.w;
      float p4 = __expf(e1.x - ma1.x) * ia1.x;
      float p5 = __expf(e1.y - ma1.y) * ia1.y;
      float p6 = __expf(e1.z - ma1.z) * ia1.z;
      float p7 = __expf(e1.w - ma1.w) * ia1.w;
      float s8 = ((p0 + p1) + (p2 + p3)) + ((p4 + p5) + (p6 + p7));
      if (it == 0) colpart0 += s8; else colpart1 += s8;
      uint32 w0 = (uint32)f2b(p0) | ((uint32)f2b(p1) << 16);
      uint32 w1 = (uint32)f2b(p2) | ((uint32)f2b(p3) << 16);
      uint32 w2 = (uint32)f2b(p4) | ((uint32)f2b(p5) << 16);
      uint32 w3 = (uint32)f2b(p6) | ((uint32)f2b(p7) << 16);
      *(uint4*)&Bs[r * 32 + kg] = make_uint4(w0, w1, w2, w3);
    }
    __syncthreads();
    s8v af[4], bf[4];
    #pragma unroll
    for (int i = 0; i < 4; i++)
      af[i] = *(const s8v*)&As[(wm * 64 + i * 16 + p) * 32 + q * 8];
    #pragma unroll
    for (int j = 0; j < 4; j++)
      bf[j] = *(const s8v*)&Bs[(wn * 64 + j * 16 + p) * 32 + q * 8];
    #pragma unroll
    for (int i = 0; i < 4; i++)
      #pragma unroll
      for (int j = 0; j < 4; j++)
        acc[i][j] = __builtin_amdgcn_mfma_f32_16x16x32_bf16(af[i], bf[j], acc[i][j], 0, 0, 0);
  }
  colred[arow][t & 3] = colpart0;
  colred[64 + arow][t & 3] = colpart1;
  __syncthreads();
  float csv[4];
  #pragma unroll
  for (int j = 0; j < 4; j++) {
    int ml = wn * 64 + j * 16 + p;
    csv[j] = 1.0f / (1e-9f + colred[ml][0] + colred[ml][1] + colred[ml][2] + colred[ml][3]);
  }
  #pragma unroll
  for (int i = 0; i < 4; i++) {
    #pragma unroll
    for (int r = 0; r < 4; r++) {
      int cl = wm * 64 + i * 16 + q * 4 + r;
      int c = c0 + cl;
      #pragma unroll
      for (int j = 0; j < 4; j++) {
        int ml = wn * 64 + j * 16 + p;
        float v = acc[i][j][r] * csv[j];
        float rv = XinF[(size_t)b * xinF_bs + (size_t)c * 1024 + m0 + ml];
        smem[ml * 128 + cl] = f2b(rv - v);
      }
    }
  }
  __syncthreads();
  int rr0 = t >> 4, cg = (t & 15) * 8;
  #pragma unroll
  for (int k = 0; k < 8; k++) {
    int rr = rr0 + k * 16;
    *(float4*)(diffT + (size_t)b * 262144 + (size_t)(m0 + rr) * 256 + c0 + cg) =
        *(const float4*)&smem[rr * 128 + cg];
  }
}

// ---------------------------------------------------------------- max pool over N
__global__ void k_maxpool(const float* __restrict__ fin, float* __restrict__ pool) {
  int bo = blockIdx.x;
  const float* pp = fin + (size_t)bo * NN;
  int t = threadIdx.x;
  float m = fmaxf(fmaxf(pp[t], pp[t + 256]), fmaxf(pp[t + 512], pp[t + 768]));
  m = waveRedMax(m);
  __shared__ float red[4];
  if ((t & 63) == 0) red[t >> 6] = m;
  __syncthreads();
  if (t == 0) pool[bo] = fmaxf(fmaxf(red[0], red[1]), fmaxf(red[2], red[3]));
}

// ---------------------------------------------------------------- small FC layers fp32
__global__ void k_fc(const float* __restrict__ in, int Cc,
                     const float* __restrict__ W,
                     const float* __restrict__ bias,
                     const float* __restrict__ bng, const float* __restrict__ bnb,
                     int act, float* __restrict__ out, int O) {
  int i = blockIdx.x * 256 + threadIdx.x;
  if (i >= BB * O) return;
  int b = i / O, o = i % O;
  const float* xp = in + (size_t)b * Cc;
  const float* wp = W + (size_t)o * Cc;
  float s = 0.f;
  for (int c = 0; c < Cc; c += 4) {
    float4 xv = *(const float4*)(xp + c);
    float4 wv = *(const float4*)(wp + c);
    s += xv.x * wv.x + xv.y * wv.y + xv.z * wv.z + xv.w * wv.w;
  }
  if (bias) s += bias[o];
  const float BNS = 0.99999500003749966f;
  if (bng) s = s * (bng[o] * BNS) + bnb[o];
  if (act == 2) s = s > 0.f ? s : 0.2f * s;
  else if (act == 1) s = fmaxf(s, 0.f);
  out[i] = s;
}

// ---------------------------------------------------------------- host
extern "C" void kernel_launch(void* const* d_in, const int* in_sizes, int n_in,
                              void* d_out, int out_size, void* d_ws, size_t ws_size,
                              hipStream_t stream) {
  const float* x        = (const float*)d_in[0];
  const float* A        = (const float*)d_in[1];
  const float* P        = (const float*)d_in[2];
  const float* cl1_wr   = (const float*)d_in[3];
  const float* cl1_wi   = (const float*)d_in[4];
  const float* cl1_br   = (const float*)d_in[5];
  const float* cl1_bi   = (const float*)d_in[6];
  const float* cl2_wr   = (const float*)d_in[7];
  const float* cl2_wi   = (const float*)d_in[8];
  const float* cl2_br   = (const float*)d_in[9];
  const float* cl2_bi   = (const float*)d_in[10];
  const float* pt_c1_w  = (const float*)d_in[11];
  const float* pt_c2_w  = (const float*)d_in[12];
  const float* pt_bn1_g = (const float*)d_in[13];
  const float* pt_bn1_b = (const float*)d_in[14];
  const float* pt_bn2_g = (const float*)d_in[15];
  const float* pt_bn2_b = (const float*)d_in[16];
  const float* sa_qk_w  = (const float*)d_in[17];
  const float* sa_v_w   = (const float*)d_in[18];
  const float* sa_v_b   = (const float*)d_in[19];
  const float* sa_t_w   = (const float*)d_in[20];
  const float* sa_t_b   = (const float*)d_in[21];
  const float* sa_bn_g  = (const float*)d_in[22];
  const float* sa_bn_b  = (const float*)d_in[23];
  const float* fuse_w   = (const float*)d_in[24];
  const float* fuse_g   = (const float*)d_in[25];
  const float* fuse_b   = (const float*)d_in[26];
  const float* lin1_w   = (const float*)d_in[27];
  const float* bn6_g    = (const float*)d_in[28];
  const float* bn6_b    = (const float*)d_in[29];
  const float* lin2_w   = (const float*)d_in[30];
  const float* lin2_b   = (const float*)d_in[31];
  const float* bn7_g    = (const float*)d_in[32];
  const float* bn7_b    = (const float*)d_in[33];
  const float* lin3_w   = (const float*)d_in[34];
  const float* lin3_b   = (const float*)d_in[35];

  float* ws = (float*)d_ws;
  // ---- workspace layout (float offsets) ----
  const size_t oPts  = 0;                         // 49152
  const size_t oS    = 65536;                     // 16777216 f scratch (aliased per phase)
  const size_t oBigT = oS + 16777216;             // 10485760 (bf16 [16][1024][1280])
  const size_t oXf0  = oBigT + 10485760;          // 4194304
  const size_t oXf1  = oXf0 + 4194304;            // 4194304
  const size_t oH1T  = oXf1 + 4194304;            // 2097152 (h1T / diffT alias)
  const size_t oH2T  = oH1T + 2097152;            // 2097152
  const size_t oXkT  = oH2T + 2097152;            // 524288
  const size_t oXv   = oXkT + 524288;             // 2097152
  const size_t oAux  = oXv + 2097152;             // 8388608: phase1 eAT(4194304)+J(4194304); phase2 rmax/rinv
  const size_t oGb   = oAux + 8388608;            // 4194304 (bf16 [16384][512])
  const size_t oW1c  = oGb + 4194304;             // 131072
  const size_t oW2c  = oW1c + 131072;             // 131072
  const size_t oCb1  = oW2c + 131072;             // 512
  const size_t oCb2  = oCb1 + 512;                // 512
  const size_t oPool = oCb2 + 512;                // 16384
  const size_t oFc1  = oPool + 16384;             // 8192
  const size_t oFc2  = oFc1 + 8192;               // 4096
  const size_t oWp   = oFc2 + 4096;               // bf16 weight pool

  float*  pts  = ws + oPts;
  // scratch S aliases: phase1 eA|Mj ; then G1b|G2b ; then E ; then fuseO
  float2* eA   = (float2*)(ws + oS);              // 4194304 float2 (33.5 MB)
  float2* Mj   = (float2*)(ws + oS + 8388608);    // fp32 [16][1024][512] = float2 [bn][256]
  u16*    G1b  = (u16*)(ws + oS);
  u16*    G2b  = (u16*)(ws + oS + 8388608);
  float*  Ebuf = ws + oS;                         // fp32 [16][1024][1024]
  float*  fuseO= ws + oS;
  u16*    bigT = (u16*)(ws + oBigT);
  float*  Xf0  = ws + oXf0;
  float*  Xf1  = ws + oXf1;
  u16*    h1T  = (u16*)(ws + oH1T);
  u16*    diffT= (u16*)(ws + oH1T);
  u16*    h2T  = (u16*)(ws + oH2T);
  u16*    xkT  = (u16*)(ws + oXkT);
  u16*    xv   = (u16*)(ws + oXv);
  u16*    eAT  = (u16*)(ws + oAux);               // phase1
  u16*    Jb   = (u16*)(ws + oAux + 4194304);     // phase1
  float*  rmax = ws + oAux;                       // phase2 (eAT dead)
  float*  rinv = ws + oAux + 16384;
  u16*    Gb   = (u16*)(ws + oGb);
  u16*    W1c  = (u16*)(ws + oW1c);
  u16*    W2c  = (u16*)(ws + oW2c);
  float*  cb1  = ws + oCb1;
  float*  cb2  = ws + oCb2;
  float*  pool = ws + oPool;
  float*  fc1  = ws + oFc1;
  float*  fc2  = ws + oFc2;
  u16*    wp   = (u16*)(ws + oWp);
  u16* wp_pt1  = wp;                // 65536
  u16* wp_pt2  = wp + 65536;        // 65536
  u16* wp_qk   = wp + 131072;       // 4*16384
  u16* wp_v    = wp + 196608;       // 4*65536
  u16* wp_t    = wp + 458752;       // 4*65536
  u16* wp_fuse = wp + 720896;       // 1310720

  // ---- weight prep ----
  k_cast<<<256, 256, 0, stream>>>(pt_c1_w, wp_pt1, 65536);
  k_cast<<<256, 256, 0, stream>>>(pt_c2_w, wp_pt2, 65536);
  k_cast<<<256, 256, 0, stream>>>(sa_qk_w, wp_qk, 65536);
  k_cast<<<1024, 256, 0, stream>>>(sa_v_w, wp_v, 262144);
  k_cast<<<1024, 256, 0, stream>>>(sa_t_w, wp_t, 262144);
  k_cast<<<5120, 256, 0, stream>>>(fuse_w, wp_fuse, 1310720);
  k_wprep<<<1024, 256, 0, stream>>>(cl1_wr, cl1_wi, W1c);
  k_wprep<<<1024, 256, 0, stream>>>(cl2_wr, cl2_wi, W2c);
  k_cbias<<<1, 512, 0, stream>>>(cl1_br, cl1_bi, cb1);
  k_cbias<<<1, 512, 0, stream>>>(cl2_br, cl2_bi, cb2);

  // ---- VecKM: M = J @ eA via MFMA ----
  k_pts<<<64, 256, 0, stream>>>(x, pts);
  k_phase<<<16384, 256, 0, stream>>>(pts, A, eA);
  k_eat<<<2048, 256, 0, stream>>>(eA, eAT);
  k_jbuild<<<16384, 256, 0, stream>>>(pts, Jb);
  // Mj[n][512] = J[n][1024] * eAT[512][1024]^T
  k_mm<128><<<512, 256, 0, stream>>>(Jb, 1048576, 1024, eAT, 524288, 1024, 1024, 8, 4,
      nullptr, nullptr, nullptr, nullptr, 0, nullptr, 0, 0,
      (float*)Mj, 524288, 512, nullptr, 0, 0, 0, nullptr, 0, 0);
  k_norm<<<BB * NN, 256, 0, stream>>>(Mj, eA, pts, P, Gb);

  // ---- complex linears as single real MFMA GEMMs (K=512) ----
  k_mm<128><<<512, 256, 0, stream>>>(Gb, 0, 512, W1c, 0, 512, 512, 128, 4,
      nullptr, nullptr, nullptr, cb1, 1, nullptr, 0, 0,
      nullptr, 0, 0, G1b, 0, 512, 1, nullptr, 0, 0);
  k_mm<128><<<512, 256, 0, stream>>>(G1b, 0, 512, W2c, 0, 512, 512, 128, 4,
      nullptr, nullptr, nullptr, cb2, 0, nullptr, 0, 0,
      nullptr, 0, 0, G2b, 0, 512, 1, nullptr, 0, 0);
  k_g2<<<16384, 256, 0, stream>>>(G2b, bigT);

  const long bsBigT = 1310720;   // ushort units
  const long bsH256 = 262144;    // [1024][256] ushort
  const long bsXkT  = 65536;
  const long bsXvU  = 262144;    // xv bf16 [256][1024]
  const long bsF    = 262144;    // fp32 [256][1024]
  const long bsE    = 1048576;   // fp32 [1024][1024]

  // ---- pt convs ----
  k_mm<128><<<256, 256, 0, stream>>>(wp_pt1, 0, 256, bigT + 1024, bsBigT, 1280, 256, 2, 8,
      nullptr, pt_bn1_g, pt_bn1_b, nullptr, 1, nullptr, 0, 0,
      nullptr, 0, 0, nullptr, 0, 0, 0, h1T, bsH256, 256);
  k_mm<128><<<256, 256, 0, stream>>>(wp_pt2, 0, 256, h1T, bsH256, 256, 256, 2, 8,
      nullptr, pt_bn2_g, pt_bn2_b, nullptr, 1, nullptr, 0, 0,
      Xf0, bsF, 1024, nullptr, 0, 0, 0, h2T, bsH256, 256);

  // ---- 4 SA layers ----
  for (int i = 0; i < 4; i++) {
    const u16* XinT   = (i == 0) ? h2T : (bigT + (i - 1) * 256);
    long       xinT_bs= (i == 0) ? bsH256 : bsBigT;
    int        xinT_ld= (i == 0) ? 256 : 1280;
    float*     XinF   = (i & 1) ? Xf1 : Xf0;
    float*     XoutF  = (i & 1) ? Xf0 : Xf1;
    const u16* qkw = wp_qk + (size_t)i * 16384;
    const u16* vw  = wp_v + (size_t)i * 65536;
    const u16* tw  = wp_t + (size_t)i * 65536;

    // qk conv: [64][256] -> xkT bf16 [n][64]
    k_mm<64><<<128, 256, 0, stream>>>(qkw, 0, 256, XinT, xinT_bs, xinT_ld, 256, 1, 8,
        nullptr, nullptr, nullptr, nullptr, 0, nullptr, 0, 0,
        nullptr, 0, 0, nullptr, 0, 0, 0, xkT, bsXkT, 64);
    // v conv: -> xv bf16 [c][n] (+bias)
    k_mm<128><<<256, 256, 0, stream>>>(vw, 0, 256, XinT, xinT_bs, xinT_ld, 256, 2, 8,
        sa_v_b + i * 256, nullptr, nullptr, nullptr, 0, nullptr, 0, 0,
        nullptr, 0, 0, xv, bsXvU, 1024, 0, nullptr, 0, 0);
    // energy E = xkT * xkT^T -> fp32 [n][m] (symmetric)
    k_mm<128><<<1024, 256, 0, stream>>>(xkT, bsXkT, 64, xkT, bsXkT, 64, 64, 8, 8,
        nullptr, nullptr, nullptr, nullptr, 0, nullptr, 0, 0,
        Ebuf, bsE, 1024, nullptr, 0, 0, 0, nullptr, 0, 0);
    k_rowstats<<<BB * NN, 256, 0, stream>>>(Ebuf, rmax, rinv);
    k_xratt<<<256, 256, 0, stream>>>(xv, Ebuf, rmax, rinv, XinF, bsF, diffT);
    // t conv: relu(bn(tw@diff + tb)) + Xin -> XoutF fp32 + bigT slice bf16
    k_mm<128><<<256, 256, 0, stream>>>(tw, 0, 256, diffT, bsH256, 256, 256, 2, 8,
        sa_t_b + i * 256, sa_bn_g + i * 256, sa_bn_b + i * 256, nullptr, 1,
        XinF, bsF, 0,
        XoutF, bsF, 1024, nullptr, 0, 0, 0, bigT + i * 256, bsBigT, 1280);
  }

  // ---- fuse conv + pool ----
  k_mm<128><<<1024, 256, 0, stream>>>(wp_fuse, 0, 1280, bigT, bsBigT, 1280, 1280, 8, 8,
      nullptr, fuse_g, fuse_b, nullptr, 2, nullptr, 0, 0,
      fuseO, 1048576, 1024, nullptr, 0, 0, 0, nullptr, 0, 0);
  k_maxpool<<<BB * 1024, 256, 0, stream>>>(fuseO, pool);

  // ---- MLP head ----
  k_fc<<<32, 256, 0, stream>>>(pool, 1024, lin1_w, nullptr, bn6_g, bn6_b, 2, fc1, 512);
  k_fc<<<16, 256, 0, stream>>>(fc1, 512, lin2_w, lin2_b, bn7_g, bn7_b, 2, fc2, 256);
  k_fc<<<3, 256, 0, stream>>>(fc2, 256, lin3_w, lin3_b, nullptr, nullptr, 0, (float*)d_out, 40);
}